// Round 5
// baseline (75.101 us; speedup 1.0000x reference)
//
#include <hip/hip_runtime.h>

#define BUCKETS_MASK ((1u << 21) - 1u)
#define RES_F 0.025f

typedef float f4 __attribute__((ext_vector_type(4)));

__global__ __launch_bounds__(256) void infer_hashgrid_kernel(
    const float* __restrict__ pts,
    const f4* __restrict__ vf4,         // voxel_features viewed as [V][8] f4
    const int* __restrict__ hash2vox,
    const float* __restrict__ smin,
    f4* __restrict__ out4,              // out viewed as [N][8] f4
    int n_half)                         // n_pts / 2
{
    const unsigned P0 = 1u, P1 = 2654435761u, P2 = 805459861u;

    int tid = blockIdx.x * blockDim.x + threadIdx.x;
    int g  = tid >> 3;          // point-pair index
    int dq = tid & 7;           // lane-in-group: feature quad AND "my" corner id
    if (g >= n_half) return;

    int pa = g;                 // point A
    int pb = g + n_half;        // point B (keeps per-wave stores contiguous)

    float sx = smin[0], sy = smin[1], sz = smin[2];

    float pax = pts[pa * 3 + 0];
    float pay = pts[pa * 3 + 1];
    float paz = pts[pa * 3 + 2];
    float pbx = pts[pb * 3 + 0];
    float pby = pts[pb * 3 + 1];
    float pbz = pts[pb * 3 + 2];

    // IEEE float32 division to bit-match numpy's (pts - smin)/RES before floor
    float qax = (pax - sx) / RES_F, qay = (pay - sy) / RES_F, qaz = (paz - sz) / RES_F;
    float qbx = (pbx - sx) / RES_F, qby = (pby - sy) / RES_F, qbz = (pbz - sz) / RES_F;

    float bax = floorf(qax), bay = floorf(qay), baz = floorf(qaz);
    float bbx = floorf(qbx), bby = floorf(qby), bbz = floorf(qbz);
    float fax = qax - bax, fay = qay - bay, faz = qaz - baz;
    float fbx = qbx - bbx, fby = qby - bby, fbz = qbz - bbz;

    unsigned ha = (unsigned)bax * P0 + (unsigned)bay * P1 + (unsigned)baz * P2;
    unsigned hb = (unsigned)bbx * P0 + (unsigned)bby * P1 + (unsigned)bbz * P2;

    // Lane-specialized hash lookup: lane dq loads ITS corner's vid only
    // (2 loads/thread instead of 16; same distinct cache lines fetched).
    unsigned mcx = dq & 1u, mcy = (dq >> 1) & 1u, mcz = (dq >> 2) & 1u;
    unsigned mdh = (mcx ? P0 : 0u) + (mcy ? P1 : 0u) + (mcz ? P2 : 0u);
    int vida_m = hash2vox[(ha + mdh) & BUCKETS_MASK];
    int vidb_m = hash2vox[(hb + mdh) & BUCKETS_MASK];

    // Broadcast all 8 corners' vids within the 8-lane group.
    int vida[8], vidb[8];
#pragma unroll
    for (int c = 0; c < 8; ++c) {
        vida[c] = __shfl(vida_m, c, 8);
        vidb[c] = __shfl(vidb_m, c, 8);
    }

    // Issue ALL 16 feature gathers (clamped address, no branch).
    f4 fa[8], fb[8];
#pragma unroll
    for (int c = 0; c < 8; ++c) {
        int va = vida[c] >= 0 ? vida[c] : 0;
        int vb = vidb[c] >= 0 ? vidb[c] : 0;
        fa[c] = vf4[(size_t)va * 8 + dq];
        fb[c] = vf4[(size_t)vb * 8 + dq];
    }

    // Keep all 16 loads in flight: compiler may not sink loads past this
    // nor hoist the consumer FMAs above it.
    __builtin_amdgcn_sched_barrier(0);

    float wax[2] = {1.0f - fax, fax}, way[2] = {1.0f - fay, fay}, waz[2] = {1.0f - faz, faz};
    float wbx[2] = {1.0f - fbx, fbx}, wby[2] = {1.0f - fby, fby}, wbz[2] = {1.0f - fbz, fbz};

    f4 ra = {0.f, 0.f, 0.f, 0.f};
    f4 rb = {0.f, 0.f, 0.f, 0.f};
#pragma unroll
    for (int c = 0; c < 8; ++c) {
        unsigned cx = c & 1u, cy = (c >> 1) & 1u, cz = (c >> 2) & 1u;
        float wa = (vida[c] >= 0) ? (wax[cx] * way[cy] * waz[cz]) : 0.0f;
        float wb = (vidb[c] >= 0) ? (wbx[cx] * wby[cy] * wbz[cz]) : 0.0f;
        ra += fa[c] * wa;
        rb += fb[c] * wb;
    }

    // Write-once output: nontemporal so the 64MB stream doesn't thrash L3.
    __builtin_nontemporal_store(ra, &out4[(size_t)pa * 8 + dq]);
    __builtin_nontemporal_store(rb, &out4[(size_t)pb * 8 + dq]);
}

extern "C" void kernel_launch(void* const* d_in, const int* in_sizes, int n_in,
                              void* d_out, int out_size, void* d_ws, size_t ws_size,
                              hipStream_t stream) {
    const float* pts      = (const float*)d_in[0];
    const f4*    vf4      = (const f4*)d_in[1];
    const int*   hash2vox = (const int*)d_in[2];
    const float* smin     = (const float*)d_in[3];
    f4* out4 = (f4*)d_out;

    int n_pts = in_sizes[0] / 3;
    int n_half = n_pts / 2;
    int total_threads = n_half * 8;
    int block = 256;
    int grid = (total_threads + block - 1) / block;

    infer_hashgrid_kernel<<<grid, block, 0, stream>>>(pts, vf4, hash2vox, smin, out4, n_half);
}